// Round 5
// baseline (353.346 us; speedup 1.0000x reference)
//
#include <hip/hip_runtime.h>

// SMPL body model forward.
// R4: k_reg moved to bf16 MFMA (k_regm) fed by k_lbs v2, which holds lbsw in
// VGPRs, loops 16 n per block (16x less lbsw traffic), reads A[n] via uniform
// s_loads, and writes verts directly in bf16 [n][c][v] (the MFMA B layout).
// R3 pose GEMM (k_gemm/k_bt/k_pf2) kept.

constexpr int N   = 512;
constexpr int V   = 6890;
constexpr int V3  = V * 3;        // 20670
constexpr int NJ  = 24;
constexpr int NB  = 10;
constexpr int NP  = 207;
constexpr int NK  = 95;
constexpr int KP  = 224;          // padded K for pose GEMM
constexpr int VP2 = 6912;         // V padded to 32*216 for reg MFMA

// workspace layout (float offsets)
constexpr size_t VP_OFF    = 0;                               // N*V3 v_posed fp32
constexpr size_t SCALE_OFF = (size_t)N * V3;                  // N
constexpr size_t SJ_OFF    = SCALE_OFF + N;                   // NB*72
constexpr size_t JT_OFF    = SJ_OFF + (size_t)NB * 72;        // 72
constexpr size_t J_OFF     = JT_OFF + 72;                     // N*72
constexpr size_t A_OFF     = J_OFF + (size_t)N * 72;          // N*288
constexpr size_t BF_OFF    = A_OFF + (size_t)N * 288;         // bf16 region start
// bf16 region (ushort offsets)
constexpr size_t APF_U     = 0;                               // [N][KP]
constexpr size_t BP_U      = (size_t)N * KP;                  // [20672][KP]
constexpr int    BP_COLS   = 20672;
constexpr size_t RB_U      = BP_U + (size_t)BP_COLS * KP;     // reg_bf [96][VP2]
constexpr size_t VB_U      = RB_U + (size_t)96 * VP2;         // verts_bf [N][3][VP2]

typedef short s16x8 __attribute__((ext_vector_type(8)));
typedef float f32x4 __attribute__((ext_vector_type(4)));

__device__ inline unsigned short f2bf(float f) {
    unsigned u = __float_as_uint(f);
    u += 0x7fffu + ((u >> 16) & 1u);   // round-to-nearest-even
    return (unsigned short)(u >> 16);
}

// ---------------------------------------------------------------------------
__global__ __launch_bounds__(256) void k_pre(const float* __restrict__ jreg,
                                             const float* __restrict__ sd,
                                             const float* __restrict__ vt,
                                             float* __restrict__ ws) {
    int jc = blockIdx.x;
    int j = jc / 3, c = jc % 3;
    int tid = threadIdx.x;
    float acc[NB + 1];
#pragma unroll
    for (int t = 0; t <= NB; ++t) acc[t] = 0.f;
    for (int v = tid; v < V; v += 256) {
        float w = jreg[(size_t)j * V + v];
        int col = v * 3 + c;
#pragma unroll
        for (int k = 0; k < NB; ++k) acc[k] += w * sd[(size_t)k * V3 + col];
        acc[NB] += w * vt[col];
    }
    __shared__ float red[256];
    for (int t = 0; t <= NB; ++t) {
        red[tid] = acc[t];
        __syncthreads();
        for (int s = 128; s > 0; s >>= 1) {
            if (tid < s) red[tid] += red[tid + s];
            __syncthreads();
        }
        if (tid == 0) {
            if (t < NB) ws[SJ_OFF + (size_t)t * 72 + jc] = red[0];
            else        ws[JT_OFF + jc] = red[0];
        }
        __syncthreads();
    }
}

// ---------------------------------------------------------------------------
__global__ __launch_bounds__(256) void k_scale(const float* __restrict__ betas,
                                               const float* __restrict__ vt,
                                               const float* __restrict__ sd,
                                               float* __restrict__ ws) {
    int n = blockIdx.x * 256 + threadIdx.x;
    if (n >= N) return;
    const int idx[4] = {2802 * 3 + 1, 6262 * 3 + 1, 2237 * 3 + 1, 6728 * 3 + 1};
    float b[NB];
#pragma unroll
    for (int k = 0; k < NB; ++k) b[k] = betas[n * NB + k];
    float vals[4];
#pragma unroll
    for (int t = 0; t < 4; ++t) {
        float a = vt[idx[t]];
#pragma unroll
        for (int k = 0; k < NB; ++k) a += b[k] * sd[(size_t)k * V3 + idx[t]];
        vals[t] = a;
    }
    float h = vals[0] + vals[1] - vals[2] - vals[3];
    ws[SCALE_OFF + n] = 1.66f / h;
}

// ---------------------------------------------------------------------------
__global__ __launch_bounds__(256) void k_joints(const float* __restrict__ betas,
                                                float* __restrict__ ws) {
    int t = blockIdx.x * 256 + threadIdx.x;
    if (t >= N * 72) return;
    int n = t / 72, jc = t - n * 72;
    float a = ws[JT_OFF + jc];
#pragma unroll
    for (int k = 0; k < NB; ++k) a += betas[n * NB + k] * ws[SJ_OFF + (size_t)k * 72 + jc];
    ws[J_OFF + t] = ws[SCALE_OFF + n] * a;
}

// ---------------------------------------------------------------------------
__global__ __launch_bounds__(64) void k_fk(const float* __restrict__ pose,
                                           float* __restrict__ ws) {
    int n = blockIdx.x;
    int tid = threadIdx.x;
    __shared__ float G[NJ * 12];
    __shared__ float Jl[NJ * 3];
    for (int e = tid; e < 72; e += 64) Jl[e] = ws[J_OFF + (size_t)n * 72 + e];
    __syncthreads();
    const int par[NJ] = {0,0,0,0,1,2,3,4,5,6,7,8,9,9,9,12,13,14,16,17,18,19,20,21};
    if (tid < 12) {
        int r = tid >> 2, c = tid & 3;
        G[tid] = (c < 3) ? pose[(size_t)n * 216 + r * 3 + c] : Jl[r];
    }
    __syncthreads();
    for (int i = 1; i < NJ; ++i) {
        int p = par[i];
        if (tid < 12) {
            int r = tid >> 2, c = tid & 3;
            const float* gp = &G[p * 12 + r * 4];
            float v;
            if (c < 3) {
                const float* Ri = pose + (size_t)n * 216 + i * 9;
                v = gp[0] * Ri[0 * 3 + c] + gp[1] * Ri[1 * 3 + c] + gp[2] * Ri[2 * 3 + c];
            } else {
                float t0 = Jl[i * 3 + 0] - Jl[p * 3 + 0];
                float t1 = Jl[i * 3 + 1] - Jl[p * 3 + 1];
                float t2 = Jl[i * 3 + 2] - Jl[p * 3 + 2];
                v = gp[0] * t0 + gp[1] * t1 + gp[2] * t2 + gp[3];
            }
            G[i * 12 + tid] = v;
        }
        __syncthreads();
    }
    for (int idx = tid; idx < 288; idx += 64) {
        int j = idx / 12, rc = idx - j * 12;
        int r = rc >> 2, c = rc & 3;
        float v;
        if (c < 3) v = G[j * 12 + rc];
        else {
            const float* g = &G[j * 12 + r * 4];
            v = g[3] - (g[0] * Jl[j * 3 + 0] + g[1] * Jl[j * 3 + 1] + g[2] * Jl[j * 3 + 2]);
        }
        ws[A_OFF + (size_t)n * 288 + idx] = v;
    }
}

// ---------------------------------------------------------------------------
// A build for pose GEMM: apf[n][k] bf16.
__global__ __launch_bounds__(256) void k_pf2(const float* __restrict__ pose,
                                             const float* __restrict__ betas,
                                             const float* __restrict__ ws,
                                             unsigned short* __restrict__ apf) {
    int n = blockIdx.x;
    int k = threadIdx.x;
    if (k >= KP) return;
    float v = 0.f;
    if (k < NP) {
        v = pose[(size_t)n * 216 + 9 + k];
        int km = k % 9;
        if (km == 0 || km == 4 || km == 8) v -= 1.f;
    } else if (k < NP + NB) {
        v = ws[SCALE_OFF + n] * betas[n * NB + (k - NP)];
    }
    apf[(size_t)n * KP + k] = f2bf(v);
}

// ---------------------------------------------------------------------------
// B build for pose GEMM: bp[col][k] bf16, k-minor (LDS transpose).
__global__ __launch_bounds__(256) void k_bt(const float* __restrict__ pdirs,
                                            const float* __restrict__ sd,
                                            unsigned short* __restrict__ bp) {
    __shared__ unsigned short t[KP * 64];
    int tid = threadIdx.x;
    int c0 = blockIdx.x * 64;
#pragma unroll 4
    for (int i = 0; i < 56; ++i) {
        int e = tid + 256 * i;
        int k = e >> 6, cl = e & 63;
        int col = c0 + cl;
        float v = 0.f;
        if (col < V3) {
            if (k < NP) v = pdirs[(size_t)k * V3 + col];
            else if (k < NP + NB) v = sd[(size_t)(k - NP) * V3 + col];
        }
        t[k * 64 + cl] = f2bf(v);
    }
    __syncthreads();
    for (int i = 0; i < 7; ++i) {
        int e = tid + 256 * i;
        int cl = e & 63, kc = e >> 6;
        s16x8 r;
#pragma unroll
        for (int j = 0; j < 8; ++j) r[j] = (short)t[(kc * 8 + j) * 64 + cl];
        *reinterpret_cast<s16x8*>(&bp[(size_t)(c0 + cl) * KP + kc * 8]) = r;
    }
}

// ---------------------------------------------------------------------------
// Pose MFMA GEMM: vp[n][col] = A[n][:224].B[:224][col] + scale[n]*vt[col]
__global__ __launch_bounds__(256) void k_gemm(const unsigned short* __restrict__ apf,
                                              const unsigned short* __restrict__ bp,
                                              const float* __restrict__ vt,
                                              const float* __restrict__ ws,
                                              float* __restrict__ vp) {
    int tid = threadIdx.x;
    int lane = tid & 63;
    int w = tid >> 6;
    int m = lane & 15, q = lane >> 4;
    int n0 = blockIdx.y * 64 + w * 16;
    int c0 = blockIdx.x * 64;

    const unsigned short* arow = apf + (size_t)(n0 + m) * KP + q * 8;
    const unsigned short* b0 = bp + (size_t)(c0 + m) * KP + q * 8;
    const unsigned short* b1 = b0 + 16 * KP;
    const unsigned short* b2 = b0 + 32 * KP;
    const unsigned short* b3 = b0 + 48 * KP;

    f32x4 acc0 = {0.f, 0.f, 0.f, 0.f};
    f32x4 acc1 = acc0, acc2 = acc0, acc3 = acc0;
#pragma unroll
    for (int kk = 0; kk < 7; ++kk) {
        s16x8 a = *reinterpret_cast<const s16x8*>(arow + kk * 32);
        acc0 = __builtin_amdgcn_mfma_f32_16x16x32_bf16(
            a, *reinterpret_cast<const s16x8*>(b0 + kk * 32), acc0, 0, 0, 0);
        acc1 = __builtin_amdgcn_mfma_f32_16x16x32_bf16(
            a, *reinterpret_cast<const s16x8*>(b1 + kk * 32), acc1, 0, 0, 0);
        acc2 = __builtin_amdgcn_mfma_f32_16x16x32_bf16(
            a, *reinterpret_cast<const s16x8*>(b2 + kk * 32), acc2, 0, 0, 0);
        acc3 = __builtin_amdgcn_mfma_f32_16x16x32_bf16(
            a, *reinterpret_cast<const s16x8*>(b3 + kk * 32), acc3, 0, 0, 0);
    }
    float sc[4];
#pragma unroll
    for (int r = 0; r < 4; ++r) sc[r] = ws[SCALE_OFF + n0 + q * 4 + r];

    f32x4 accs[4] = {acc0, acc1, acc2, acc3};
#pragma unroll
    for (int ct = 0; ct < 4; ++ct) {
        int col = c0 + ct * 16 + m;
        if (col < V3) {
            float vtc = vt[col];
#pragma unroll
            for (int r = 0; r < 4; ++r) {
                int n = n0 + q * 4 + r;
                vp[(size_t)n * V3 + col] = accs[ct][r] + sc[r] * vtc;
            }
        }
    }
}

// ---------------------------------------------------------------------------
// reg matrix -> bf16 [96][VP2] (row 95 and v>=V zero)
__global__ __launch_bounds__(256) void k_regbf(const float* __restrict__ b25,
                                               const float* __restrict__ face,
                                               unsigned short* __restrict__ rb) {
    int t = blockIdx.x * 256 + threadIdx.x;
    if (t >= 96 * VP2) return;
    int k = t / VP2, v = t - k * VP2;
    float val = 0.f;
    if (v < V && k < NK)
        val = (k < 25) ? b25[(size_t)k * V + v] : face[(size_t)(k - 25) * V + v];
    rb[t] = f2bf(val);
}

// ---------------------------------------------------------------------------
// k_lbs v2: weights in VGPRs, 16 n per block, A[n] via uniform s_loads,
// writes verts bf16 [n][c][v] (v-minor, padded to VP2 with zeros).
__global__ __launch_bounds__(256) void k_lbs(const float* __restrict__ lbsw,
                                             const float* __restrict__ trans,
                                             const float* __restrict__ ws,
                                             unsigned short* __restrict__ vb) {
    int tid = threadIdx.x;
    int v = blockIdx.x * 256 + tid;      // 0..VP2-1
    int n0 = blockIdx.y * 16;
    bool vv = (v < V);
    float w[NJ];
#pragma unroll
    for (int j = 0; j < NJ; ++j) w[j] = vv ? lbsw[(size_t)v * NJ + j] : 0.f;

    for (int nn = 0; nn < 16; ++nn) {
        int n = n0 + nn;
        const float* An = ws + A_OFF + (size_t)n * 288;
        float T[12];
#pragma unroll
        for (int e = 0; e < 12; ++e) T[e] = 0.f;
#pragma unroll
        for (int j = 0; j < NJ; ++j) {
            float4 a0 = *reinterpret_cast<const float4*>(An + j * 12);
            float4 a1 = *reinterpret_cast<const float4*>(An + j * 12 + 4);
            float4 a2 = *reinterpret_cast<const float4*>(An + j * 12 + 8);
            float wj = w[j];
            T[0] += wj * a0.x;  T[1] += wj * a0.y;  T[2]  += wj * a0.z;  T[3]  += wj * a0.w;
            T[4] += wj * a1.x;  T[5] += wj * a1.y;  T[6]  += wj * a1.z;  T[7]  += wj * a1.w;
            T[8] += wj * a2.x;  T[9] += wj * a2.y;  T[10] += wj * a2.z;  T[11] += wj * a2.w;
        }
        float p0 = 0.f, p1 = 0.f, p2 = 0.f;
        if (vv) {
            const float* vp = ws + VP_OFF + (size_t)n * V3 + (size_t)v * 3;
            p0 = vp[0]; p1 = vp[1]; p2 = vp[2];
        }
        float x = T[0] * p0 + T[1] * p1 + T[2]  * p2 + T[3]  + trans[n * 3 + 0];
        float y = T[4] * p0 + T[5] * p1 + T[6]  * p2 + T[7]  + trans[n * 3 + 1];
        float z = T[8] * p0 + T[9] * p1 + T[10] * p2 + T[11] + trans[n * 3 + 2];
        if (!vv) { x = 0.f; y = 0.f; z = 0.f; }
        size_t base = (size_t)n * 3 * VP2 + v;
        vb[base]            = f2bf(x);
        vb[base + VP2]      = f2bf(y);
        vb[base + 2 * VP2]  = f2bf(z);
    }
}

// ---------------------------------------------------------------------------
// k_regm: out[k][(n,c)] = reg_bf[96][VP2] @ verts_bf^T.  MFMA 16x16x32.
// Grid (96 nc-tiles, 6 k-tiles); block 4 waves, each a K-quarter; LDS combine.
__global__ __launch_bounds__(256) void k_regm(const unsigned short* __restrict__ rb,
                                              const unsigned short* __restrict__ vb,
                                              float* __restrict__ out) {
    int tid = threadIdx.x;
    int lane = tid & 63, w = tid >> 6;
    int m = lane & 15, q = lane >> 4;
    int kt = blockIdx.y, nct = blockIdx.x;

    const unsigned short* arow = rb + (size_t)(kt * 16 + m) * VP2 + q * 8;
    const unsigned short* brow = vb + (size_t)(nct * 16 + m) * VP2 + q * 8;
    int v0 = w * (VP2 / 4);              // 1728 per wave

    f32x4 acc = {0.f, 0.f, 0.f, 0.f};
    for (int s = 0; s < VP2 / 4 / 32; ++s) {   // 54 K-steps
        int off = v0 + s * 32;
        s16x8 a = *reinterpret_cast<const s16x8*>(arow + off);
        s16x8 b = *reinterpret_cast<const s16x8*>(brow + off);
        acc = __builtin_amdgcn_mfma_f32_16x16x32_bf16(a, b, acc, 0, 0, 0);
    }
    __shared__ float sm[4 * 256];
#pragma unroll
    for (int r = 0; r < 4; ++r)
        sm[w * 256 + (q * 4 + r) * 16 + m] = acc[r];
    __syncthreads();
    float s = sm[tid] + sm[256 + tid] + sm[512 + tid] + sm[768 + tid];
    int k = kt * 16 + (tid >> 4);
    int nc = nct * 16 + (tid & 15);
    if (k < NK) {
        int n = nc / 3, c = nc - n * 3;
        out[(size_t)n * (NK * 3) + k * 3 + c] = s;
    }
}

// ---------------------------------------------------------------------------
extern "C" void kernel_launch(void* const* d_in, const int* in_sizes, int n_in,
                              void* d_out, int out_size, void* d_ws, size_t ws_size,
                              hipStream_t stream) {
    const float* pose  = (const float*)d_in[0];
    const float* betas = (const float*)d_in[1];
    const float* trans = (const float*)d_in[2];
    const float* vt    = (const float*)d_in[3];
    const float* sd    = (const float*)d_in[4];
    const float* jreg  = (const float*)d_in[5];
    const float* pdirs = (const float*)d_in[6];
    const float* lbsw  = (const float*)d_in[7];
    const float* b25   = (const float*)d_in[8];
    const float* face  = (const float*)d_in[9];
    float* ws  = (float*)d_ws;
    float* out = (float*)d_out;
    unsigned short* bf  = (unsigned short*)(ws + BF_OFF);
    unsigned short* apf = bf + APF_U;
    unsigned short* bp  = bf + BP_U;
    unsigned short* rb  = bf + RB_U;
    unsigned short* vb  = bf + VB_U;

    k_pre   <<<72, 256, 0, stream>>>(jreg, sd, vt, ws);
    k_scale <<<2, 256, 0, stream>>>(betas, vt, sd, ws);
    k_joints<<<(N * 72 + 255) / 256, 256, 0, stream>>>(betas, ws);
    k_fk    <<<N, 64, 0, stream>>>(pose, ws);
    k_bt    <<<BP_COLS / 64, 256, 0, stream>>>(pdirs, sd, bp);
    k_pf2   <<<N, 256, 0, stream>>>(pose, betas, ws, apf);
    k_regbf <<<(96 * VP2 + 255) / 256, 256, 0, stream>>>(b25, face, rb);
    k_gemm  <<<dim3(BP_COLS / 64, N / 64), 256, 0, stream>>>(apf, bp, vt, ws, ws + VP_OFF);
    k_lbs   <<<dim3(VP2 / 256, N / 16), 256, 0, stream>>>(lbsw, trans, ws, vb);
    k_regm  <<<dim3(96, 6), 256, 0, stream>>>(rb, vb, out);
}

// Round 6
// 328.003 us; speedup vs baseline: 1.0773x; 1.0773x over previous
//
#include <hip/hip_runtime.h>

// SMPL body model forward.
// R5: k_lbs v3 — j-loop outermost (no w[] array to spill; R4's version was
// scratch/reload-bound at VGPR=28), 4 n per block for occupancy, lbsw
// pre-transposed (k_wt) for coalesced weight loads. Rest unchanged from R4.

constexpr int N   = 512;
constexpr int V   = 6890;
constexpr int V3  = V * 3;        // 20670
constexpr int NJ  = 24;
constexpr int NB  = 10;
constexpr int NP  = 207;
constexpr int NK  = 95;
constexpr int KP  = 224;          // padded K for pose GEMM
constexpr int VP2 = 6912;         // V padded for reg MFMA (27*256)

// workspace layout (float offsets)
constexpr size_t VP_OFF    = 0;                               // N*V3 v_posed fp32
constexpr size_t SCALE_OFF = (size_t)N * V3;                  // N
constexpr size_t SJ_OFF    = SCALE_OFF + N;                   // NB*72
constexpr size_t JT_OFF    = SJ_OFF + (size_t)NB * 72;        // 72
constexpr size_t J_OFF     = JT_OFF + 72;                     // N*72
constexpr size_t A_OFF     = J_OFF + (size_t)N * 72;          // N*288
constexpr size_t BF_OFF    = A_OFF + (size_t)N * 288;         // bf16 region start
// bf16 region (ushort offsets)
constexpr size_t APF_U     = 0;                               // [N][KP]
constexpr size_t BP_U      = (size_t)N * KP;
constexpr int    BP_COLS   = 20672;
constexpr size_t RB_U      = BP_U + (size_t)BP_COLS * KP;     // reg_bf [96][VP2]
constexpr size_t VB_U      = RB_U + (size_t)96 * VP2;         // verts_bf [N][3][VP2]
constexpr size_t BF_END_U  = VB_U + (size_t)N * 3 * VP2;
constexpr size_t WT_OFF    = BF_OFF + (BF_END_U + 1) / 2;     // wbt [24][VP2] fp32

typedef short s16x8 __attribute__((ext_vector_type(8)));
typedef float f32x4 __attribute__((ext_vector_type(4)));

__device__ inline unsigned short f2bf(float f) {
    unsigned u = __float_as_uint(f);
    u += 0x7fffu + ((u >> 16) & 1u);   // round-to-nearest-even
    return (unsigned short)(u >> 16);
}

// ---------------------------------------------------------------------------
__global__ __launch_bounds__(256) void k_pre(const float* __restrict__ jreg,
                                             const float* __restrict__ sd,
                                             const float* __restrict__ vt,
                                             float* __restrict__ ws) {
    int jc = blockIdx.x;
    int j = jc / 3, c = jc % 3;
    int tid = threadIdx.x;
    float acc[NB + 1];
#pragma unroll
    for (int t = 0; t <= NB; ++t) acc[t] = 0.f;
    for (int v = tid; v < V; v += 256) {
        float w = jreg[(size_t)j * V + v];
        int col = v * 3 + c;
#pragma unroll
        for (int k = 0; k < NB; ++k) acc[k] += w * sd[(size_t)k * V3 + col];
        acc[NB] += w * vt[col];
    }
    __shared__ float red[256];
    for (int t = 0; t <= NB; ++t) {
        red[tid] = acc[t];
        __syncthreads();
        for (int s = 128; s > 0; s >>= 1) {
            if (tid < s) red[tid] += red[tid + s];
            __syncthreads();
        }
        if (tid == 0) {
            if (t < NB) ws[SJ_OFF + (size_t)t * 72 + jc] = red[0];
            else        ws[JT_OFF + jc] = red[0];
        }
        __syncthreads();
    }
}

// ---------------------------------------------------------------------------
__global__ __launch_bounds__(256) void k_scale(const float* __restrict__ betas,
                                               const float* __restrict__ vt,
                                               const float* __restrict__ sd,
                                               float* __restrict__ ws) {
    int n = blockIdx.x * 256 + threadIdx.x;
    if (n >= N) return;
    const int idx[4] = {2802 * 3 + 1, 6262 * 3 + 1, 2237 * 3 + 1, 6728 * 3 + 1};
    float b[NB];
#pragma unroll
    for (int k = 0; k < NB; ++k) b[k] = betas[n * NB + k];
    float vals[4];
#pragma unroll
    for (int t = 0; t < 4; ++t) {
        float a = vt[idx[t]];
#pragma unroll
        for (int k = 0; k < NB; ++k) a += b[k] * sd[(size_t)k * V3 + idx[t]];
        vals[t] = a;
    }
    float h = vals[0] + vals[1] - vals[2] - vals[3];
    ws[SCALE_OFF + n] = 1.66f / h;
}

// ---------------------------------------------------------------------------
__global__ __launch_bounds__(256) void k_joints(const float* __restrict__ betas,
                                                float* __restrict__ ws) {
    int t = blockIdx.x * 256 + threadIdx.x;
    if (t >= N * 72) return;
    int n = t / 72, jc = t - n * 72;
    float a = ws[JT_OFF + jc];
#pragma unroll
    for (int k = 0; k < NB; ++k) a += betas[n * NB + k] * ws[SJ_OFF + (size_t)k * 72 + jc];
    ws[J_OFF + t] = ws[SCALE_OFF + n] * a;
}

// ---------------------------------------------------------------------------
__global__ __launch_bounds__(64) void k_fk(const float* __restrict__ pose,
                                           float* __restrict__ ws) {
    int n = blockIdx.x;
    int tid = threadIdx.x;
    __shared__ float G[NJ * 12];
    __shared__ float Jl[NJ * 3];
    for (int e = tid; e < 72; e += 64) Jl[e] = ws[J_OFF + (size_t)n * 72 + e];
    __syncthreads();
    const int par[NJ] = {0,0,0,0,1,2,3,4,5,6,7,8,9,9,9,12,13,14,16,17,18,19,20,21};
    if (tid < 12) {
        int r = tid >> 2, c = tid & 3;
        G[tid] = (c < 3) ? pose[(size_t)n * 216 + r * 3 + c] : Jl[r];
    }
    __syncthreads();
    for (int i = 1; i < NJ; ++i) {
        int p = par[i];
        if (tid < 12) {
            int r = tid >> 2, c = tid & 3;
            const float* gp = &G[p * 12 + r * 4];
            float v;
            if (c < 3) {
                const float* Ri = pose + (size_t)n * 216 + i * 9;
                v = gp[0] * Ri[0 * 3 + c] + gp[1] * Ri[1 * 3 + c] + gp[2] * Ri[2 * 3 + c];
            } else {
                float t0 = Jl[i * 3 + 0] - Jl[p * 3 + 0];
                float t1 = Jl[i * 3 + 1] - Jl[p * 3 + 1];
                float t2 = Jl[i * 3 + 2] - Jl[p * 3 + 2];
                v = gp[0] * t0 + gp[1] * t1 + gp[2] * t2 + gp[3];
            }
            G[i * 12 + tid] = v;
        }
        __syncthreads();
    }
    for (int idx = tid; idx < 288; idx += 64) {
        int j = idx / 12, rc = idx - j * 12;
        int r = rc >> 2, c = rc & 3;
        float v;
        if (c < 3) v = G[j * 12 + rc];
        else {
            const float* g = &G[j * 12 + r * 4];
            v = g[3] - (g[0] * Jl[j * 3 + 0] + g[1] * Jl[j * 3 + 1] + g[2] * Jl[j * 3 + 2]);
        }
        ws[A_OFF + (size_t)n * 288 + idx] = v;
    }
}

// ---------------------------------------------------------------------------
__global__ __launch_bounds__(256) void k_pf2(const float* __restrict__ pose,
                                             const float* __restrict__ betas,
                                             const float* __restrict__ ws,
                                             unsigned short* __restrict__ apf) {
    int n = blockIdx.x;
    int k = threadIdx.x;
    if (k >= KP) return;
    float v = 0.f;
    if (k < NP) {
        v = pose[(size_t)n * 216 + 9 + k];
        int km = k % 9;
        if (km == 0 || km == 4 || km == 8) v -= 1.f;
    } else if (k < NP + NB) {
        v = ws[SCALE_OFF + n] * betas[n * NB + (k - NP)];
    }
    apf[(size_t)n * KP + k] = f2bf(v);
}

// ---------------------------------------------------------------------------
__global__ __launch_bounds__(256) void k_bt(const float* __restrict__ pdirs,
                                            const float* __restrict__ sd,
                                            unsigned short* __restrict__ bp) {
    __shared__ unsigned short t[KP * 64];
    int tid = threadIdx.x;
    int c0 = blockIdx.x * 64;
#pragma unroll 4
    for (int i = 0; i < 56; ++i) {
        int e = tid + 256 * i;
        int k = e >> 6, cl = e & 63;
        int col = c0 + cl;
        float v = 0.f;
        if (col < V3) {
            if (k < NP) v = pdirs[(size_t)k * V3 + col];
            else if (k < NP + NB) v = sd[(size_t)(k - NP) * V3 + col];
        }
        t[k * 64 + cl] = f2bf(v);
    }
    __syncthreads();
    for (int i = 0; i < 7; ++i) {
        int e = tid + 256 * i;
        int cl = e & 63, kc = e >> 6;
        s16x8 r;
#pragma unroll
        for (int j = 0; j < 8; ++j) r[j] = (short)t[(kc * 8 + j) * 64 + cl];
        *reinterpret_cast<s16x8*>(&bp[(size_t)(c0 + cl) * KP + kc * 8]) = r;
    }
}

// ---------------------------------------------------------------------------
__global__ __launch_bounds__(256) void k_gemm(const unsigned short* __restrict__ apf,
                                              const unsigned short* __restrict__ bp,
                                              const float* __restrict__ vt,
                                              const float* __restrict__ ws,
                                              float* __restrict__ vp) {
    int tid = threadIdx.x;
    int lane = tid & 63;
    int w = tid >> 6;
    int m = lane & 15, q = lane >> 4;
    int n0 = blockIdx.y * 64 + w * 16;
    int c0 = blockIdx.x * 64;

    const unsigned short* arow = apf + (size_t)(n0 + m) * KP + q * 8;
    const unsigned short* b0 = bp + (size_t)(c0 + m) * KP + q * 8;
    const unsigned short* b1 = b0 + 16 * KP;
    const unsigned short* b2 = b0 + 32 * KP;
    const unsigned short* b3 = b0 + 48 * KP;

    f32x4 acc0 = {0.f, 0.f, 0.f, 0.f};
    f32x4 acc1 = acc0, acc2 = acc0, acc3 = acc0;
#pragma unroll
    for (int kk = 0; kk < 7; ++kk) {
        s16x8 a = *reinterpret_cast<const s16x8*>(arow + kk * 32);
        acc0 = __builtin_amdgcn_mfma_f32_16x16x32_bf16(
            a, *reinterpret_cast<const s16x8*>(b0 + kk * 32), acc0, 0, 0, 0);
        acc1 = __builtin_amdgcn_mfma_f32_16x16x32_bf16(
            a, *reinterpret_cast<const s16x8*>(b1 + kk * 32), acc1, 0, 0, 0);
        acc2 = __builtin_amdgcn_mfma_f32_16x16x32_bf16(
            a, *reinterpret_cast<const s16x8*>(b2 + kk * 32), acc2, 0, 0, 0);
        acc3 = __builtin_amdgcn_mfma_f32_16x16x32_bf16(
            a, *reinterpret_cast<const s16x8*>(b3 + kk * 32), acc3, 0, 0, 0);
    }
    float sc[4];
#pragma unroll
    for (int r = 0; r < 4; ++r) sc[r] = ws[SCALE_OFF + n0 + q * 4 + r];

    f32x4 accs[4] = {acc0, acc1, acc2, acc3};
#pragma unroll
    for (int ct = 0; ct < 4; ++ct) {
        int col = c0 + ct * 16 + m;
        if (col < V3) {
            float vtc = vt[col];
#pragma unroll
            for (int r = 0; r < 4; ++r) {
                int n = n0 + q * 4 + r;
                vp[(size_t)n * V3 + col] = accs[ct][r] + sc[r] * vtc;
            }
        }
    }
}

// ---------------------------------------------------------------------------
__global__ __launch_bounds__(256) void k_regbf(const float* __restrict__ b25,
                                               const float* __restrict__ face,
                                               unsigned short* __restrict__ rb) {
    int t = blockIdx.x * 256 + threadIdx.x;
    if (t >= 96 * VP2) return;
    int k = t / VP2, v = t - k * VP2;
    float val = 0.f;
    if (v < V && k < NK)
        val = (k < 25) ? b25[(size_t)k * V + v] : face[(size_t)(k - 25) * V + v];
    rb[t] = f2bf(val);
}

// ---------------------------------------------------------------------------
// lbsw transpose: wbt[j][v] = lbsw[v][j], v >= V -> 0. 27 blocks.
__global__ __launch_bounds__(256) void k_wt(const float* __restrict__ lbsw,
                                            float* __restrict__ wbt) {
    __shared__ float t[256 * 25];
    int tid = threadIdx.x;
    int v0 = blockIdx.x * 256;
    for (int e = tid; e < 256 * 24; e += 256) {
        int g = v0 * 24 + e;
        float val = (g < V * NJ) ? lbsw[g] : 0.f;
        int vv = e / 24, j = e - vv * 24;
        t[vv * 25 + j] = val;
    }
    __syncthreads();
    for (int j = 0; j < NJ; ++j)
        wbt[(size_t)j * VP2 + v0 + tid] = t[tid * 25 + j];
}

// ---------------------------------------------------------------------------
// k_lbs v3: j outermost (no spillable array), 4 n per block, T[4][12] in regs,
// A via uniform s_loads, weights coalesced from wbt. Writes verts bf16
// [n][c][v] (v-minor, padded) = MFMA B layout for k_regm.
__global__ __launch_bounds__(256) void k_lbs(const float* __restrict__ wbt,
                                             const float* __restrict__ trans,
                                             const float* __restrict__ ws,
                                             unsigned short* __restrict__ vb) {
    int tid = threadIdx.x;
    int v = blockIdx.x * 256 + tid;      // < VP2
    int n0 = blockIdx.y * 4;

    float T[4][12];
#pragma unroll
    for (int nn = 0; nn < 4; ++nn)
#pragma unroll
        for (int e = 0; e < 12; ++e) T[nn][e] = 0.f;

    const float* A0 = ws + A_OFF + (size_t)n0 * 288;
#pragma unroll
    for (int j = 0; j < NJ; ++j) {
        float wj = wbt[(size_t)j * VP2 + v];
#pragma unroll
        for (int nn = 0; nn < 4; ++nn) {
            const float* An = A0 + nn * 288 + j * 12;    // block-uniform -> s_load
            float4 a0 = *reinterpret_cast<const float4*>(An);
            float4 a1 = *reinterpret_cast<const float4*>(An + 4);
            float4 a2 = *reinterpret_cast<const float4*>(An + 8);
            T[nn][0] += wj * a0.x;  T[nn][1] += wj * a0.y;  T[nn][2]  += wj * a0.z;  T[nn][3]  += wj * a0.w;
            T[nn][4] += wj * a1.x;  T[nn][5] += wj * a1.y;  T[nn][6]  += wj * a1.z;  T[nn][7]  += wj * a1.w;
            T[nn][8] += wj * a2.x;  T[nn][9] += wj * a2.y;  T[nn][10] += wj * a2.z;  T[nn][11] += wj * a2.w;
        }
    }
    bool vv = (v < V);
#pragma unroll
    for (int nn = 0; nn < 4; ++nn) {
        int n = n0 + nn;
        float p0 = 0.f, p1 = 0.f, p2 = 0.f;
        if (vv) {
            const float* vp = ws + VP_OFF + (size_t)n * V3 + (size_t)v * 3;
            p0 = vp[0]; p1 = vp[1]; p2 = vp[2];
        }
        float x = T[nn][0] * p0 + T[nn][1] * p1 + T[nn][2]  * p2 + T[nn][3]  + trans[n * 3 + 0];
        float y = T[nn][4] * p0 + T[nn][5] * p1 + T[nn][6]  * p2 + T[nn][7]  + trans[n * 3 + 1];
        float z = T[nn][8] * p0 + T[nn][9] * p1 + T[nn][10] * p2 + T[nn][11] + trans[n * 3 + 2];
        if (!vv) { x = 0.f; y = 0.f; z = 0.f; }
        size_t base = (size_t)n * 3 * VP2 + v;
        vb[base]           = f2bf(x);
        vb[base + VP2]     = f2bf(y);
        vb[base + 2 * VP2] = f2bf(z);
    }
}

// ---------------------------------------------------------------------------
// k_regm: out[k][(n,c)] = reg_bf @ verts_bf^T.  MFMA 16x16x32, 4-wave K-split.
__global__ __launch_bounds__(256) void k_regm(const unsigned short* __restrict__ rb,
                                              const unsigned short* __restrict__ vb,
                                              float* __restrict__ out) {
    int tid = threadIdx.x;
    int lane = tid & 63, w = tid >> 6;
    int m = lane & 15, q = lane >> 4;
    int kt = blockIdx.y, nct = blockIdx.x;

    const unsigned short* arow = rb + (size_t)(kt * 16 + m) * VP2 + q * 8;
    const unsigned short* brow = vb + (size_t)(nct * 16 + m) * VP2 + q * 8;
    int v0 = w * (VP2 / 4);

    f32x4 acc = {0.f, 0.f, 0.f, 0.f};
    for (int s = 0; s < VP2 / 4 / 32; ++s) {
        int off = v0 + s * 32;
        s16x8 a = *reinterpret_cast<const s16x8*>(arow + off);
        s16x8 b = *reinterpret_cast<const s16x8*>(brow + off);
        acc = __builtin_amdgcn_mfma_f32_16x16x32_bf16(a, b, acc, 0, 0, 0);
    }
    __shared__ float sm[4 * 256];
#pragma unroll
    for (int r = 0; r < 4; ++r)
        sm[w * 256 + (q * 4 + r) * 16 + m] = acc[r];
    __syncthreads();
    float s = sm[tid] + sm[256 + tid] + sm[512 + tid] + sm[768 + tid];
    int k = kt * 16 + (tid >> 4);
    int nc = nct * 16 + (tid & 15);
    if (k < NK) {
        int n = nc / 3, c = nc - n * 3;
        out[(size_t)n * (NK * 3) + k * 3 + c] = s;
    }
}

// ---------------------------------------------------------------------------
extern "C" void kernel_launch(void* const* d_in, const int* in_sizes, int n_in,
                              void* d_out, int out_size, void* d_ws, size_t ws_size,
                              hipStream_t stream) {
    const float* pose  = (const float*)d_in[0];
    const float* betas = (const float*)d_in[1];
    const float* trans = (const float*)d_in[2];
    const float* vt    = (const float*)d_in[3];
    const float* sd    = (const float*)d_in[4];
    const float* jreg  = (const float*)d_in[5];
    const float* pdirs = (const float*)d_in[6];
    const float* lbsw  = (const float*)d_in[7];
    const float* b25   = (const float*)d_in[8];
    const float* face  = (const float*)d_in[9];
    float* ws  = (float*)d_ws;
    float* out = (float*)d_out;
    unsigned short* bf  = (unsigned short*)(ws + BF_OFF);
    unsigned short* apf = bf + APF_U;
    unsigned short* bp  = bf + BP_U;
    unsigned short* rb  = bf + RB_U;
    unsigned short* vb  = bf + VB_U;
    float* wbt = ws + WT_OFF;

    k_pre   <<<72, 256, 0, stream>>>(jreg, sd, vt, ws);
    k_scale <<<2, 256, 0, stream>>>(betas, vt, sd, ws);
    k_joints<<<(N * 72 + 255) / 256, 256, 0, stream>>>(betas, ws);
    k_fk    <<<N, 64, 0, stream>>>(pose, ws);
    k_bt    <<<BP_COLS / 64, 256, 0, stream>>>(pdirs, sd, bp);
    k_pf2   <<<N, 256, 0, stream>>>(pose, betas, ws, apf);
    k_regbf <<<(96 * VP2 + 255) / 256, 256, 0, stream>>>(b25, face, rb);
    k_wt    <<<VP2 / 256, 256, 0, stream>>>(lbsw, wbt);
    k_gemm  <<<dim3(BP_COLS / 64, N / 64), 256, 0, stream>>>(apf, bp, vt, ws, ws + VP_OFF);
    k_lbs   <<<dim3(VP2 / 256, N / 4), 256, 0, stream>>>(wbt, trans, ws, vb);
    k_regm  <<<dim3(96, 6), 256, 0, stream>>>(rb, vb, out);
}

// Round 7
// 275.248 us; speedup vs baseline: 1.2837x; 1.1917x over previous
//
#include <hip/hip_runtime.h>

// SMPL body model forward.
// R6: k_lbs v4 — q-formulation: verts = sum_j w[v,j]*(A[n,j]@[p;1]) + trans.
// Only 3 accumulators + 3 p live per n (R4/R5 showed any >=12-reg accumulator
// array gets mangled by the allocator: VGPR pinned at 28-32 with 5x VALU
// overhead). 8 n per block, j-loop unrolled, A rows wave-uniform -> SGPRs.
// Rest unchanged from R5.

constexpr int N   = 512;
constexpr int V   = 6890;
constexpr int V3  = V * 3;        // 20670
constexpr int NJ  = 24;
constexpr int NB  = 10;
constexpr int NP  = 207;
constexpr int NK  = 95;
constexpr int KP  = 224;          // padded K for pose GEMM
constexpr int VP2 = 6912;         // V padded for reg MFMA (27*256)

// workspace layout (float offsets)
constexpr size_t VP_OFF    = 0;                               // N*V3 v_posed fp32
constexpr size_t SCALE_OFF = (size_t)N * V3;                  // N
constexpr size_t SJ_OFF    = SCALE_OFF + N;                   // NB*72
constexpr size_t JT_OFF    = SJ_OFF + (size_t)NB * 72;        // 72
constexpr size_t J_OFF     = JT_OFF + 72;                     // N*72
constexpr size_t A_OFF     = J_OFF + (size_t)N * 72;          // N*288
constexpr size_t BF_OFF    = A_OFF + (size_t)N * 288;         // bf16 region start
// bf16 region (ushort offsets)
constexpr size_t APF_U     = 0;                               // [N][KP]
constexpr size_t BP_U      = (size_t)N * KP;
constexpr int    BP_COLS   = 20672;
constexpr size_t RB_U      = BP_U + (size_t)BP_COLS * KP;     // reg_bf [96][VP2]
constexpr size_t VB_U      = RB_U + (size_t)96 * VP2;         // verts_bf [N][3][VP2]
constexpr size_t BF_END_U  = VB_U + (size_t)N * 3 * VP2;
constexpr size_t WT_OFF    = BF_OFF + (BF_END_U + 1) / 2;     // wbt [24][VP2] fp32

typedef short s16x8 __attribute__((ext_vector_type(8)));
typedef float f32x4 __attribute__((ext_vector_type(4)));

__device__ inline unsigned short f2bf(float f) {
    unsigned u = __float_as_uint(f);
    u += 0x7fffu + ((u >> 16) & 1u);   // round-to-nearest-even
    return (unsigned short)(u >> 16);
}

// ---------------------------------------------------------------------------
__global__ __launch_bounds__(256) void k_pre(const float* __restrict__ jreg,
                                             const float* __restrict__ sd,
                                             const float* __restrict__ vt,
                                             float* __restrict__ ws) {
    int jc = blockIdx.x;
    int j = jc / 3, c = jc % 3;
    int tid = threadIdx.x;
    float acc[NB + 1];
#pragma unroll
    for (int t = 0; t <= NB; ++t) acc[t] = 0.f;
    for (int v = tid; v < V; v += 256) {
        float w = jreg[(size_t)j * V + v];
        int col = v * 3 + c;
#pragma unroll
        for (int k = 0; k < NB; ++k) acc[k] += w * sd[(size_t)k * V3 + col];
        acc[NB] += w * vt[col];
    }
    __shared__ float red[256];
    for (int t = 0; t <= NB; ++t) {
        red[tid] = acc[t];
        __syncthreads();
        for (int s = 128; s > 0; s >>= 1) {
            if (tid < s) red[tid] += red[tid + s];
            __syncthreads();
        }
        if (tid == 0) {
            if (t < NB) ws[SJ_OFF + (size_t)t * 72 + jc] = red[0];
            else        ws[JT_OFF + jc] = red[0];
        }
        __syncthreads();
    }
}

// ---------------------------------------------------------------------------
__global__ __launch_bounds__(256) void k_scale(const float* __restrict__ betas,
                                               const float* __restrict__ vt,
                                               const float* __restrict__ sd,
                                               float* __restrict__ ws) {
    int n = blockIdx.x * 256 + threadIdx.x;
    if (n >= N) return;
    const int idx[4] = {2802 * 3 + 1, 6262 * 3 + 1, 2237 * 3 + 1, 6728 * 3 + 1};
    float b[NB];
#pragma unroll
    for (int k = 0; k < NB; ++k) b[k] = betas[n * NB + k];
    float vals[4];
#pragma unroll
    for (int t = 0; t < 4; ++t) {
        float a = vt[idx[t]];
#pragma unroll
        for (int k = 0; k < NB; ++k) a += b[k] * sd[(size_t)k * V3 + idx[t]];
        vals[t] = a;
    }
    float h = vals[0] + vals[1] - vals[2] - vals[3];
    ws[SCALE_OFF + n] = 1.66f / h;
}

// ---------------------------------------------------------------------------
__global__ __launch_bounds__(256) void k_joints(const float* __restrict__ betas,
                                                float* __restrict__ ws) {
    int t = blockIdx.x * 256 + threadIdx.x;
    if (t >= N * 72) return;
    int n = t / 72, jc = t - n * 72;
    float a = ws[JT_OFF + jc];
#pragma unroll
    for (int k = 0; k < NB; ++k) a += betas[n * NB + k] * ws[SJ_OFF + (size_t)k * 72 + jc];
    ws[J_OFF + t] = ws[SCALE_OFF + n] * a;
}

// ---------------------------------------------------------------------------
__global__ __launch_bounds__(64) void k_fk(const float* __restrict__ pose,
                                           float* __restrict__ ws) {
    int n = blockIdx.x;
    int tid = threadIdx.x;
    __shared__ float G[NJ * 12];
    __shared__ float Jl[NJ * 3];
    for (int e = tid; e < 72; e += 64) Jl[e] = ws[J_OFF + (size_t)n * 72 + e];
    __syncthreads();
    const int par[NJ] = {0,0,0,0,1,2,3,4,5,6,7,8,9,9,9,12,13,14,16,17,18,19,20,21};
    if (tid < 12) {
        int r = tid >> 2, c = tid & 3;
        G[tid] = (c < 3) ? pose[(size_t)n * 216 + r * 3 + c] : Jl[r];
    }
    __syncthreads();
    for (int i = 1; i < NJ; ++i) {
        int p = par[i];
        if (tid < 12) {
            int r = tid >> 2, c = tid & 3;
            const float* gp = &G[p * 12 + r * 4];
            float v;
            if (c < 3) {
                const float* Ri = pose + (size_t)n * 216 + i * 9;
                v = gp[0] * Ri[0 * 3 + c] + gp[1] * Ri[1 * 3 + c] + gp[2] * Ri[2 * 3 + c];
            } else {
                float t0 = Jl[i * 3 + 0] - Jl[p * 3 + 0];
                float t1 = Jl[i * 3 + 1] - Jl[p * 3 + 1];
                float t2 = Jl[i * 3 + 2] - Jl[p * 3 + 2];
                v = gp[0] * t0 + gp[1] * t1 + gp[2] * t2 + gp[3];
            }
            G[i * 12 + tid] = v;
        }
        __syncthreads();
    }
    for (int idx = tid; idx < 288; idx += 64) {
        int j = idx / 12, rc = idx - j * 12;
        int r = rc >> 2, c = rc & 3;
        float v;
        if (c < 3) v = G[j * 12 + rc];
        else {
            const float* g = &G[j * 12 + r * 4];
            v = g[3] - (g[0] * Jl[j * 3 + 0] + g[1] * Jl[j * 3 + 1] + g[2] * Jl[j * 3 + 2]);
        }
        ws[A_OFF + (size_t)n * 288 + idx] = v;
    }
}

// ---------------------------------------------------------------------------
__global__ __launch_bounds__(256) void k_pf2(const float* __restrict__ pose,
                                             const float* __restrict__ betas,
                                             const float* __restrict__ ws,
                                             unsigned short* __restrict__ apf) {
    int n = blockIdx.x;
    int k = threadIdx.x;
    if (k >= KP) return;
    float v = 0.f;
    if (k < NP) {
        v = pose[(size_t)n * 216 + 9 + k];
        int km = k % 9;
        if (km == 0 || km == 4 || km == 8) v -= 1.f;
    } else if (k < NP + NB) {
        v = ws[SCALE_OFF + n] * betas[n * NB + (k - NP)];
    }
    apf[(size_t)n * KP + k] = f2bf(v);
}

// ---------------------------------------------------------------------------
__global__ __launch_bounds__(256) void k_bt(const float* __restrict__ pdirs,
                                            const float* __restrict__ sd,
                                            unsigned short* __restrict__ bp) {
    __shared__ unsigned short t[KP * 64];
    int tid = threadIdx.x;
    int c0 = blockIdx.x * 64;
#pragma unroll 4
    for (int i = 0; i < 56; ++i) {
        int e = tid + 256 * i;
        int k = e >> 6, cl = e & 63;
        int col = c0 + cl;
        float v = 0.f;
        if (col < V3) {
            if (k < NP) v = pdirs[(size_t)k * V3 + col];
            else if (k < NP + NB) v = sd[(size_t)(k - NP) * V3 + col];
        }
        t[k * 64 + cl] = f2bf(v);
    }
    __syncthreads();
    for (int i = 0; i < 7; ++i) {
        int e = tid + 256 * i;
        int cl = e & 63, kc = e >> 6;
        s16x8 r;
#pragma unroll
        for (int j = 0; j < 8; ++j) r[j] = (short)t[(kc * 8 + j) * 64 + cl];
        *reinterpret_cast<s16x8*>(&bp[(size_t)(c0 + cl) * KP + kc * 8]) = r;
    }
}

// ---------------------------------------------------------------------------
__global__ __launch_bounds__(256) void k_gemm(const unsigned short* __restrict__ apf,
                                              const unsigned short* __restrict__ bp,
                                              const float* __restrict__ vt,
                                              const float* __restrict__ ws,
                                              float* __restrict__ vp) {
    int tid = threadIdx.x;
    int lane = tid & 63;
    int w = tid >> 6;
    int m = lane & 15, q = lane >> 4;
    int n0 = blockIdx.y * 64 + w * 16;
    int c0 = blockIdx.x * 64;

    const unsigned short* arow = apf + (size_t)(n0 + m) * KP + q * 8;
    const unsigned short* b0 = bp + (size_t)(c0 + m) * KP + q * 8;
    const unsigned short* b1 = b0 + 16 * KP;
    const unsigned short* b2 = b0 + 32 * KP;
    const unsigned short* b3 = b0 + 48 * KP;

    f32x4 acc0 = {0.f, 0.f, 0.f, 0.f};
    f32x4 acc1 = acc0, acc2 = acc0, acc3 = acc0;
#pragma unroll
    for (int kk = 0; kk < 7; ++kk) {
        s16x8 a = *reinterpret_cast<const s16x8*>(arow + kk * 32);
        acc0 = __builtin_amdgcn_mfma_f32_16x16x32_bf16(
            a, *reinterpret_cast<const s16x8*>(b0 + kk * 32), acc0, 0, 0, 0);
        acc1 = __builtin_amdgcn_mfma_f32_16x16x32_bf16(
            a, *reinterpret_cast<const s16x8*>(b1 + kk * 32), acc1, 0, 0, 0);
        acc2 = __builtin_amdgcn_mfma_f32_16x16x32_bf16(
            a, *reinterpret_cast<const s16x8*>(b2 + kk * 32), acc2, 0, 0, 0);
        acc3 = __builtin_amdgcn_mfma_f32_16x16x32_bf16(
            a, *reinterpret_cast<const s16x8*>(b3 + kk * 32), acc3, 0, 0, 0);
    }
    float sc[4];
#pragma unroll
    for (int r = 0; r < 4; ++r) sc[r] = ws[SCALE_OFF + n0 + q * 4 + r];

    f32x4 accs[4] = {acc0, acc1, acc2, acc3};
#pragma unroll
    for (int ct = 0; ct < 4; ++ct) {
        int col = c0 + ct * 16 + m;
        if (col < V3) {
            float vtc = vt[col];
#pragma unroll
            for (int r = 0; r < 4; ++r) {
                int n = n0 + q * 4 + r;
                vp[(size_t)n * V3 + col] = accs[ct][r] + sc[r] * vtc;
            }
        }
    }
}

// ---------------------------------------------------------------------------
__global__ __launch_bounds__(256) void k_regbf(const float* __restrict__ b25,
                                               const float* __restrict__ face,
                                               unsigned short* __restrict__ rb) {
    int t = blockIdx.x * 256 + threadIdx.x;
    if (t >= 96 * VP2) return;
    int k = t / VP2, v = t - k * VP2;
    float val = 0.f;
    if (v < V && k < NK)
        val = (k < 25) ? b25[(size_t)k * V + v] : face[(size_t)(k - 25) * V + v];
    rb[t] = f2bf(val);
}

// ---------------------------------------------------------------------------
// lbsw transpose: wbt[j][v] = lbsw[v][j], v >= V -> 0. 27 blocks.
__global__ __launch_bounds__(256) void k_wt(const float* __restrict__ lbsw,
                                            float* __restrict__ wbt) {
    __shared__ float t[256 * 25];
    int tid = threadIdx.x;
    int v0 = blockIdx.x * 256;
    for (int e = tid; e < 256 * 24; e += 256) {
        int g = v0 * 24 + e;
        float val = (g < V * NJ) ? lbsw[g] : 0.f;
        int vv = e / 24, j = e - vv * 24;
        t[vv * 25 + j] = val;
    }
    __syncthreads();
    for (int j = 0; j < NJ; ++j)
        wbt[(size_t)j * VP2 + v0 + tid] = t[tid * 25 + j];
}

// ---------------------------------------------------------------------------
// k_lbs v4 (q-formulation): verts = sum_j w[v,j]*(A[n,j]@[p;1]) + trans.
// 3 accs + 3 p live; A rows wave-uniform (s_load); 8 n per block.
// Writes verts bf16 [n][c][v] (v-minor, pad 0) = MFMA B layout for k_regm.
__global__ __launch_bounds__(256) void k_lbs(const float* __restrict__ wbt,
                                             const float* __restrict__ trans,
                                             const float* __restrict__ ws,
                                             unsigned short* __restrict__ vb) {
    int tid = threadIdx.x;
    int v = blockIdx.x * 256 + tid;      // < VP2
    int n0 = blockIdx.y * 8;
    bool vv = (v < V);

    for (int nn = 0; nn < 8; ++nn) {
        int n = n0 + nn;
        const float* An = ws + A_OFF + (size_t)n * 288;   // block-uniform
        float p0 = 0.f, p1 = 0.f, p2 = 0.f;
        if (vv) {
            const float* vp = ws + VP_OFF + (size_t)n * V3 + (size_t)v * 3;
            p0 = vp[0]; p1 = vp[1]; p2 = vp[2];
        }
        float ax = trans[n * 3 + 0];
        float ay = trans[n * 3 + 1];
        float az = trans[n * 3 + 2];
#pragma unroll
        for (int j = 0; j < NJ; ++j) {
            float wj = wbt[(size_t)j * VP2 + v];
            const float* a = An + j * 12;
            float qx = a[0] * p0 + a[1]  * p1 + a[2]  * p2 + a[3];
            float qy = a[4] * p0 + a[5]  * p1 + a[6]  * p2 + a[7];
            float qz = a[8] * p0 + a[9]  * p1 + a[10] * p2 + a[11];
            ax += wj * qx;
            ay += wj * qy;
            az += wj * qz;
        }
        if (!vv) { ax = 0.f; ay = 0.f; az = 0.f; }
        size_t base = (size_t)n * 3 * VP2 + v;
        vb[base]           = f2bf(ax);
        vb[base + VP2]     = f2bf(ay);
        vb[base + 2 * VP2] = f2bf(az);
    }
}

// ---------------------------------------------------------------------------
// k_regm: out[k][(n,c)] = reg_bf @ verts_bf^T.  MFMA 16x16x32, 4-wave K-split.
__global__ __launch_bounds__(256) void k_regm(const unsigned short* __restrict__ rb,
                                              const unsigned short* __restrict__ vb,
                                              float* __restrict__ out) {
    int tid = threadIdx.x;
    int lane = tid & 63, w = tid >> 6;
    int m = lane & 15, q = lane >> 4;
    int kt = blockIdx.y, nct = blockIdx.x;

    const unsigned short* arow = rb + (size_t)(kt * 16 + m) * VP2 + q * 8;
    const unsigned short* brow = vb + (size_t)(nct * 16 + m) * VP2 + q * 8;
    int v0 = w * (VP2 / 4);

    f32x4 acc = {0.f, 0.f, 0.f, 0.f};
    for (int s = 0; s < VP2 / 4 / 32; ++s) {
        int off = v0 + s * 32;
        s16x8 a = *reinterpret_cast<const s16x8*>(arow + off);
        s16x8 b = *reinterpret_cast<const s16x8*>(brow + off);
        acc = __builtin_amdgcn_mfma_f32_16x16x32_bf16(a, b, acc, 0, 0, 0);
    }
    __shared__ float sm[4 * 256];
#pragma unroll
    for (int r = 0; r < 4; ++r)
        sm[w * 256 + (q * 4 + r) * 16 + m] = acc[r];
    __syncthreads();
    float s = sm[tid] + sm[256 + tid] + sm[512 + tid] + sm[768 + tid];
    int k = kt * 16 + (tid >> 4);
    int nc = nct * 16 + (tid & 15);
    if (k < NK) {
        int n = nc / 3, c = nc - n * 3;
        out[(size_t)n * (NK * 3) + k * 3 + c] = s;
    }
}

// ---------------------------------------------------------------------------
extern "C" void kernel_launch(void* const* d_in, const int* in_sizes, int n_in,
                              void* d_out, int out_size, void* d_ws, size_t ws_size,
                              hipStream_t stream) {
    const float* pose  = (const float*)d_in[0];
    const float* betas = (const float*)d_in[1];
    const float* trans = (const float*)d_in[2];
    const float* vt    = (const float*)d_in[3];
    const float* sd    = (const float*)d_in[4];
    const float* jreg  = (const float*)d_in[5];
    const float* pdirs = (const float*)d_in[6];
    const float* lbsw  = (const float*)d_in[7];
    const float* b25   = (const float*)d_in[8];
    const float* face  = (const float*)d_in[9];
    float* ws  = (float*)d_ws;
    float* out = (float*)d_out;
    unsigned short* bf  = (unsigned short*)(ws + BF_OFF);
    unsigned short* apf = bf + APF_U;
    unsigned short* bp  = bf + BP_U;
    unsigned short* rb  = bf + RB_U;
    unsigned short* vb  = bf + VB_U;
    float* wbt = ws + WT_OFF;

    k_pre   <<<72, 256, 0, stream>>>(jreg, sd, vt, ws);
    k_scale <<<2, 256, 0, stream>>>(betas, vt, sd, ws);
    k_joints<<<(N * 72 + 255) / 256, 256, 0, stream>>>(betas, ws);
    k_fk    <<<N, 64, 0, stream>>>(pose, ws);
    k_bt    <<<BP_COLS / 64, 256, 0, stream>>>(pdirs, sd, bp);
    k_pf2   <<<N, 256, 0, stream>>>(pose, betas, ws, apf);
    k_regbf <<<(96 * VP2 + 255) / 256, 256, 0, stream>>>(b25, face, rb);
    k_wt    <<<VP2 / 256, 256, 0, stream>>>(lbsw, wbt);
    k_gemm  <<<dim3(BP_COLS / 64, N / 64), 256, 0, stream>>>(apf, bp, vt, ws, ws + VP_OFF);
    k_lbs   <<<dim3(VP2 / 256, N / 8), 256, 0, stream>>>(wbt, trans, ws, vb);
    k_regm  <<<dim3(96, 6), 256, 0, stream>>>(rb, vb, out);
}

// Round 8
// 240.667 us; speedup vs baseline: 1.4682x; 1.1437x over previous
//
#include <hip/hip_runtime.h>

// SMPL body model forward.
// R7: pipeline consolidated 11 -> 5 kernels.
//  - k_static: all batch-independent prep (regbf | bt | wt | pre) sectioned by
//    blockIdx; pre's reduction tail now shuffle-based (1 barrier, not 11 trees).
//  - k_head: scale + joints + apf(pose_feature) + FK fused, one block per n.
//  - k_lbs: 4 n per block (2x blocks -> oversubscribed waves).
//  - k_gemm / k_regm unchanged (R3/R4 MFMA kernels).

constexpr int N   = 512;
constexpr int V   = 6890;
constexpr int V3  = V * 3;        // 20670
constexpr int NJ  = 24;
constexpr int NB  = 10;
constexpr int NP  = 207;
constexpr int NK  = 95;
constexpr int KP  = 224;          // padded K for pose GEMM
constexpr int VP2 = 6912;         // V padded for reg MFMA (27*256)

// workspace layout (float offsets)
constexpr size_t VP_OFF    = 0;                               // N*V3 v_posed fp32
constexpr size_t SCALE_OFF = (size_t)N * V3;                  // N
constexpr size_t SJ_OFF    = SCALE_OFF + N;                   // NB*72
constexpr size_t JT_OFF    = SJ_OFF + (size_t)NB * 72;        // 72
constexpr size_t J_OFF     = JT_OFF + 72;                     // N*72 (unused since R7)
constexpr size_t A_OFF     = J_OFF + (size_t)N * 72;          // N*288
constexpr size_t BF_OFF    = A_OFF + (size_t)N * 288;         // bf16 region start
// bf16 region (ushort offsets)
constexpr size_t APF_U     = 0;                               // [N][KP]
constexpr size_t BP_U      = (size_t)N * KP;
constexpr int    BP_COLS   = 20672;
constexpr size_t RB_U      = BP_U + (size_t)BP_COLS * KP;     // reg_bf [96][VP2]
constexpr size_t VB_U      = RB_U + (size_t)96 * VP2;         // verts_bf [N][3][VP2]
constexpr size_t BF_END_U  = VB_U + (size_t)N * 3 * VP2;
constexpr size_t WT_OFF    = BF_OFF + (BF_END_U + 1) / 2;     // wbt [24][VP2] fp32

// k_static section block counts
constexpr int NB_REGBF = (96 * VP2) / 256;   // 2592 (exact)
constexpr int NB_BT    = BP_COLS / 64;       // 323
constexpr int NB_WT    = VP2 / 256;          // 27
constexpr int NB_PRE   = 72;
constexpr int NB_STATIC = NB_REGBF + NB_BT + NB_WT + NB_PRE;

typedef short s16x8 __attribute__((ext_vector_type(8)));
typedef float f32x4 __attribute__((ext_vector_type(4)));

__device__ inline unsigned short f2bf(float f) {
    unsigned u = __float_as_uint(f);
    u += 0x7fffu + ((u >> 16) & 1u);   // round-to-nearest-even
    return (unsigned short)(u >> 16);
}

// ---------------------------------------------------------------------------
// k_static: sectioned batch-independent prep.
__global__ __launch_bounds__(256) void k_static(const float* __restrict__ pdirs,
                                                const float* __restrict__ sd,
                                                const float* __restrict__ jreg,
                                                const float* __restrict__ vt,
                                                const float* __restrict__ lbsw,
                                                const float* __restrict__ b25,
                                                const float* __restrict__ face,
                                                unsigned short* __restrict__ bp,
                                                unsigned short* __restrict__ rb,
                                                float* __restrict__ wbt,
                                                float* __restrict__ ws) {
    __shared__ unsigned short smem[KP * 64];     // 28 KB, reused per section
    int b = blockIdx.x;
    int tid = threadIdx.x;

    if (b < NB_REGBF) {
        // ---- regbf: reg matrix -> bf16 [96][VP2]
        int t = b * 256 + tid;
        int k = t / VP2, v = t - k * VP2;
        float val = 0.f;
        if (v < V && k < NK)
            val = (k < 25) ? b25[(size_t)k * V + v] : face[(size_t)(k - 25) * V + v];
        rb[t] = f2bf(val);
        return;
    }
    b -= NB_REGBF;
    if (b < NB_BT) {
        // ---- bt: B = [posedirs ; shapedirs] bf16 [20672][KP] k-minor
        int c0 = b * 64;
#pragma unroll 4
        for (int i = 0; i < 56; ++i) {
            int e = tid + 256 * i;
            int k = e >> 6, cl = e & 63;
            int col = c0 + cl;
            float v = 0.f;
            if (col < V3) {
                if (k < NP) v = pdirs[(size_t)k * V3 + col];
                else if (k < NP + NB) v = sd[(size_t)(k - NP) * V3 + col];
            }
            smem[k * 64 + cl] = f2bf(v);
        }
        __syncthreads();
        for (int i = 0; i < 7; ++i) {
            int e = tid + 256 * i;
            int cl = e & 63, kc = e >> 6;
            s16x8 r;
#pragma unroll
            for (int j = 0; j < 8; ++j) r[j] = (short)smem[(kc * 8 + j) * 64 + cl];
            *reinterpret_cast<s16x8*>(&bp[(size_t)(c0 + cl) * KP + kc * 8]) = r;
        }
        return;
    }
    b -= NB_BT;
    if (b < NB_WT) {
        // ---- wt: wbt[j][v] = lbsw[v][j]
        float* t = reinterpret_cast<float*>(smem);   // 25.6 KB
        int v0 = b * 256;
        for (int e = tid; e < 256 * 24; e += 256) {
            int g = v0 * 24 + e;
            float val = (g < V * NJ) ? lbsw[g] : 0.f;
            int vv = e / 24, j = e - vv * 24;
            t[vv * 25 + j] = val;
        }
        __syncthreads();
        for (int j = 0; j < NJ; ++j)
            wbt[(size_t)j * VP2 + v0 + tid] = t[tid * 25 + j];
        return;
    }
    b -= NB_WT;
    // ---- pre: SJ[k][jc], Jt[jc]; block per jc, shuffle reduce.
    int jc = b;
    int j = jc / 3, c = jc % 3;
    float acc[NB + 1];
#pragma unroll
    for (int t = 0; t <= NB; ++t) acc[t] = 0.f;
    for (int v = tid; v < V; v += 256) {
        float w = jreg[(size_t)j * V + v];
        int col = v * 3 + c;
#pragma unroll
        for (int k = 0; k < NB; ++k) acc[k] += w * sd[(size_t)k * V3 + col];
        acc[NB] += w * vt[col];
    }
    float* red = reinterpret_cast<float*>(smem);
    int lane = tid & 63, w64 = tid >> 6;
#pragma unroll
    for (int t = 0; t <= NB; ++t) {
        float a = acc[t];
#pragma unroll
        for (int s = 1; s < 64; s <<= 1) a += __shfl_xor(a, s, 64);
        if (lane == 0) red[w64 * 16 + t] = a;
    }
    __syncthreads();
    if (tid <= NB) {
        float s = red[tid] + red[16 + tid] + red[32 + tid] + red[48 + tid];
        if (tid < NB) ws[SJ_OFF + (size_t)tid * 72 + jc] = s;
        else          ws[JT_OFF + jc] = s;
    }
}

// ---------------------------------------------------------------------------
// k_head: scale + J + apf + FK, one block per n.
__global__ __launch_bounds__(256) void k_head(const float* __restrict__ pose,
                                              const float* __restrict__ betas,
                                              const float* __restrict__ vt,
                                              const float* __restrict__ sd,
                                              float* __restrict__ ws,
                                              unsigned short* __restrict__ apf) {
    int n = blockIdx.x;
    int tid = threadIdx.x;
    __shared__ float sval[4];
    __shared__ float Jl[NJ * 3];
    __shared__ float G[NJ * 12];

    const int idx4[4] = {2802 * 3 + 1, 6262 * 3 + 1, 2237 * 3 + 1, 6728 * 3 + 1};
    if (tid < 4) {
        float a = vt[idx4[tid]];
#pragma unroll
        for (int k = 0; k < NB; ++k)
            a += betas[n * NB + k] * sd[(size_t)k * V3 + idx4[tid]];
        sval[tid] = a;
    }
    __syncthreads();
    float scale = 1.66f / (sval[0] + sval[1] - sval[2] - sval[3]);
    if (tid == 0) ws[SCALE_OFF + n] = scale;

    // apf row (pose_feature | scale*betas | 0)
    if (tid < KP) {
        float v = 0.f;
        if (tid < NP) {
            v = pose[(size_t)n * 216 + 9 + tid];
            int km = tid % 9;
            if (km == 0 || km == 4 || km == 8) v -= 1.f;
        } else if (tid < NP + NB) {
            v = scale * betas[n * NB + (tid - NP)];
        }
        apf[(size_t)n * KP + tid] = f2bf(v);
    }
    // J
    if (tid < 72) {
        float a = ws[JT_OFF + tid];
#pragma unroll
        for (int k = 0; k < NB; ++k)
            a += betas[n * NB + k] * ws[SJ_OFF + (size_t)k * 72 + tid];
        Jl[tid] = scale * a;
    }
    __syncthreads();

    const int par[NJ] = {0,0,0,0,1,2,3,4,5,6,7,8,9,9,9,12,13,14,16,17,18,19,20,21};
    if (tid < 12) {
        int r = tid >> 2, c = tid & 3;
        G[tid] = (c < 3) ? pose[(size_t)n * 216 + r * 3 + c] : Jl[r];
    }
    __syncthreads();
    for (int i = 1; i < NJ; ++i) {
        int p = par[i];
        if (tid < 12) {
            int r = tid >> 2, c = tid & 3;
            const float* gp = &G[p * 12 + r * 4];
            float v;
            if (c < 3) {
                const float* Ri = pose + (size_t)n * 216 + i * 9;
                v = gp[0] * Ri[0 * 3 + c] + gp[1] * Ri[1 * 3 + c] + gp[2] * Ri[2 * 3 + c];
            } else {
                float t0 = Jl[i * 3 + 0] - Jl[p * 3 + 0];
                float t1 = Jl[i * 3 + 1] - Jl[p * 3 + 1];
                float t2 = Jl[i * 3 + 2] - Jl[p * 3 + 2];
                v = gp[0] * t0 + gp[1] * t1 + gp[2] * t2 + gp[3];
            }
            G[i * 12 + tid] = v;
        }
        __syncthreads();
    }
    for (int idx = tid; idx < 288; idx += 256) {
        int j = idx / 12, rc = idx - j * 12;
        int r = rc >> 2, c = rc & 3;
        float v;
        if (c < 3) v = G[j * 12 + rc];
        else {
            const float* g = &G[j * 12 + r * 4];
            v = g[3] - (g[0] * Jl[j * 3 + 0] + g[1] * Jl[j * 3 + 1] + g[2] * Jl[j * 3 + 2]);
        }
        ws[A_OFF + (size_t)n * 288 + idx] = v;
    }
}

// ---------------------------------------------------------------------------
// Pose MFMA GEMM: vp[n][col] = A[n][:224].B[:224][col] + scale[n]*vt[col]
__global__ __launch_bounds__(256) void k_gemm(const unsigned short* __restrict__ apf,
                                              const unsigned short* __restrict__ bp,
                                              const float* __restrict__ vt,
                                              const float* __restrict__ ws,
                                              float* __restrict__ vp) {
    int tid = threadIdx.x;
    int lane = tid & 63;
    int w = tid >> 6;
    int m = lane & 15, q = lane >> 4;
    int n0 = blockIdx.y * 64 + w * 16;
    int c0 = blockIdx.x * 64;

    const unsigned short* arow = apf + (size_t)(n0 + m) * KP + q * 8;
    const unsigned short* b0 = bp + (size_t)(c0 + m) * KP + q * 8;
    const unsigned short* b1 = b0 + 16 * KP;
    const unsigned short* b2 = b0 + 32 * KP;
    const unsigned short* b3 = b0 + 48 * KP;

    f32x4 acc0 = {0.f, 0.f, 0.f, 0.f};
    f32x4 acc1 = acc0, acc2 = acc0, acc3 = acc0;
#pragma unroll
    for (int kk = 0; kk < 7; ++kk) {
        s16x8 a = *reinterpret_cast<const s16x8*>(arow + kk * 32);
        acc0 = __builtin_amdgcn_mfma_f32_16x16x32_bf16(
            a, *reinterpret_cast<const s16x8*>(b0 + kk * 32), acc0, 0, 0, 0);
        acc1 = __builtin_amdgcn_mfma_f32_16x16x32_bf16(
            a, *reinterpret_cast<const s16x8*>(b1 + kk * 32), acc1, 0, 0, 0);
        acc2 = __builtin_amdgcn_mfma_f32_16x16x32_bf16(
            a, *reinterpret_cast<const s16x8*>(b2 + kk * 32), acc2, 0, 0, 0);
        acc3 = __builtin_amdgcn_mfma_f32_16x16x32_bf16(
            a, *reinterpret_cast<const s16x8*>(b3 + kk * 32), acc3, 0, 0, 0);
    }
    float sc[4];
#pragma unroll
    for (int r = 0; r < 4; ++r) sc[r] = ws[SCALE_OFF + n0 + q * 4 + r];

    f32x4 accs[4] = {acc0, acc1, acc2, acc3};
#pragma unroll
    for (int ct = 0; ct < 4; ++ct) {
        int col = c0 + ct * 16 + m;
        if (col < V3) {
            float vtc = vt[col];
#pragma unroll
            for (int r = 0; r < 4; ++r) {
                int n = n0 + q * 4 + r;
                vp[(size_t)n * V3 + col] = accs[ct][r] + sc[r] * vtc;
            }
        }
    }
}

// ---------------------------------------------------------------------------
// k_lbs (q-form, R6) with 4 n per block for TLP.
__global__ __launch_bounds__(256) void k_lbs(const float* __restrict__ wbt,
                                             const float* __restrict__ trans,
                                             const float* __restrict__ ws,
                                             unsigned short* __restrict__ vb) {
    int tid = threadIdx.x;
    int v = blockIdx.x * 256 + tid;      // < VP2
    int n0 = blockIdx.y * 4;
    bool vv = (v < V);

    for (int nn = 0; nn < 4; ++nn) {
        int n = n0 + nn;
        const float* An = ws + A_OFF + (size_t)n * 288;   // block-uniform
        float p0 = 0.f, p1 = 0.f, p2 = 0.f;
        if (vv) {
            const float* vp = ws + VP_OFF + (size_t)n * V3 + (size_t)v * 3;
            p0 = vp[0]; p1 = vp[1]; p2 = vp[2];
        }
        float ax = trans[n * 3 + 0];
        float ay = trans[n * 3 + 1];
        float az = trans[n * 3 + 2];
#pragma unroll
        for (int j = 0; j < NJ; ++j) {
            float wj = wbt[(size_t)j * VP2 + v];
            const float* a = An + j * 12;
            float qx = a[0] * p0 + a[1]  * p1 + a[2]  * p2 + a[3];
            float qy = a[4] * p0 + a[5]  * p1 + a[6]  * p2 + a[7];
            float qz = a[8] * p0 + a[9]  * p1 + a[10] * p2 + a[11];
            ax += wj * qx;
            ay += wj * qy;
            az += wj * qz;
        }
        if (!vv) { ax = 0.f; ay = 0.f; az = 0.f; }
        size_t base = (size_t)n * 3 * VP2 + v;
        vb[base]           = f2bf(ax);
        vb[base + VP2]     = f2bf(ay);
        vb[base + 2 * VP2] = f2bf(az);
    }
}

// ---------------------------------------------------------------------------
// k_regm: out[k][(n,c)] = reg_bf @ verts_bf^T.  MFMA 16x16x32, 4-wave K-split.
__global__ __launch_bounds__(256) void k_regm(const unsigned short* __restrict__ rb,
                                              const unsigned short* __restrict__ vb,
                                              float* __restrict__ out) {
    int tid = threadIdx.x;
    int lane = tid & 63, w = tid >> 6;
    int m = lane & 15, q = lane >> 4;
    int kt = blockIdx.y, nct = blockIdx.x;

    const unsigned short* arow = rb + (size_t)(kt * 16 + m) * VP2 + q * 8;
    const unsigned short* brow = vb + (size_t)(nct * 16 + m) * VP2 + q * 8;
    int v0 = w * (VP2 / 4);

    f32x4 acc = {0.f, 0.f, 0.f, 0.f};
    for (int s = 0; s < VP2 / 4 / 32; ++s) {
        int off = v0 + s * 32;
        s16x8 a = *reinterpret_cast<const s16x8*>(arow + off);
        s16x8 b = *reinterpret_cast<const s16x8*>(brow + off);
        acc = __builtin_amdgcn_mfma_f32_16x16x32_bf16(a, b, acc, 0, 0, 0);
    }
    __shared__ float sm[4 * 256];
#pragma unroll
    for (int r = 0; r < 4; ++r)
        sm[w * 256 + (q * 4 + r) * 16 + m] = acc[r];
    __syncthreads();
    float s = sm[tid] + sm[256 + tid] + sm[512 + tid] + sm[768 + tid];
    int k = kt * 16 + (tid >> 4);
    int nc = nct * 16 + (tid & 15);
    if (k < NK) {
        int n = nc / 3, c = nc - n * 3;
        out[(size_t)n * (NK * 3) + k * 3 + c] = s;
    }
}

// ---------------------------------------------------------------------------
extern "C" void kernel_launch(void* const* d_in, const int* in_sizes, int n_in,
                              void* d_out, int out_size, void* d_ws, size_t ws_size,
                              hipStream_t stream) {
    const float* pose  = (const float*)d_in[0];
    const float* betas = (const float*)d_in[1];
    const float* trans = (const float*)d_in[2];
    const float* vt    = (const float*)d_in[3];
    const float* sd    = (const float*)d_in[4];
    const float* jreg  = (const float*)d_in[5];
    const float* pdirs = (const float*)d_in[6];
    const float* lbsw  = (const float*)d_in[7];
    const float* b25   = (const float*)d_in[8];
    const float* face  = (const float*)d_in[9];
    float* ws  = (float*)d_ws;
    float* out = (float*)d_out;
    unsigned short* bf  = (unsigned short*)(ws + BF_OFF);
    unsigned short* apf = bf + APF_U;
    unsigned short* bp  = bf + BP_U;
    unsigned short* rb  = bf + RB_U;
    unsigned short* vb  = bf + VB_U;
    float* wbt = ws + WT_OFF;

    k_static<<<NB_STATIC, 256, 0, stream>>>(pdirs, sd, jreg, vt, lbsw, b25, face,
                                            bp, rb, wbt, ws);
    k_head  <<<N, 256, 0, stream>>>(pose, betas, vt, sd, ws, apf);
    k_gemm  <<<dim3(BP_COLS / 64, N / 64), 256, 0, stream>>>(apf, bp, vt, ws, ws + VP_OFF);
    k_lbs   <<<dim3(VP2 / 256, N / 4), 256, 0, stream>>>(wbt, trans, ws, vb);
    k_regm  <<<dim3(96, 6), 256, 0, stream>>>(rb, vb, out);
}

// Round 9
// 231.095 us; speedup vs baseline: 1.5290x; 1.0414x over previous
//
#include <hip/hip_runtime.h>

// SMPL body model forward.
// R8:
//  - k_lbs v5: j-outer (wbt amortized over 4 n), paired-v f32x2 math
//    (v_pk_fma_f32 dual-issue fp32; V even so pairs never straddle validity),
//    launch_bounds(256,4) to un-pin the register allocator.
//  - k_regm v2: all 6 k-tiles per block (rb L2-resident; vb read ONCE = 21 MB,
//    was 127 MB through L3), v-split 2 + atomicAdd.
//  - k_head: 64 threads (FK chain in one wave, barriers ~free).

constexpr int N   = 512;
constexpr int V   = 6890;
constexpr int V3  = V * 3;        // 20670
constexpr int NJ  = 24;
constexpr int NB  = 10;
constexpr int NP  = 207;
constexpr int NK  = 95;
constexpr int KP  = 224;          // padded K for pose GEMM
constexpr int VP2 = 6912;         // V padded for reg MFMA (27*256)

// workspace layout (float offsets)
constexpr size_t VP_OFF    = 0;                               // N*V3 v_posed fp32
constexpr size_t SCALE_OFF = (size_t)N * V3;                  // N
constexpr size_t SJ_OFF    = SCALE_OFF + N;                   // NB*72
constexpr size_t JT_OFF    = SJ_OFF + (size_t)NB * 72;        // 72
constexpr size_t J_OFF     = JT_OFF + 72;                     // N*72 (unused)
constexpr size_t A_OFF     = J_OFF + (size_t)N * 72;          // N*288
constexpr size_t BF_OFF    = A_OFF + (size_t)N * 288;         // bf16 region start
// bf16 region (ushort offsets)
constexpr size_t APF_U     = 0;                               // [N][KP]
constexpr size_t BP_U      = (size_t)N * KP;
constexpr int    BP_COLS   = 20672;
constexpr size_t RB_U      = BP_U + (size_t)BP_COLS * KP;     // reg_bf [96][VP2]
constexpr size_t VB_U      = RB_U + (size_t)96 * VP2;         // verts_bf [N][3][VP2]
constexpr size_t BF_END_U  = VB_U + (size_t)N * 3 * VP2;
constexpr size_t WT_OFF    = BF_OFF + (BF_END_U + 1) / 2;     // wbt [24][VP2] fp32

// k_static section block counts
constexpr int NB_REGBF = (96 * VP2) / 256;   // 2592
constexpr int NB_BT    = BP_COLS / 64;       // 323
constexpr int NB_WT    = VP2 / 256;          // 27
constexpr int NB_PRE   = 72;
constexpr int NB_STATIC = NB_REGBF + NB_BT + NB_WT + NB_PRE;

typedef short s16x8 __attribute__((ext_vector_type(8)));
typedef float f32x4 __attribute__((ext_vector_type(4)));
typedef float f32x2 __attribute__((ext_vector_type(2)));

__device__ inline unsigned short f2bf(float f) {
    unsigned u = __float_as_uint(f);
    u += 0x7fffu + ((u >> 16) & 1u);   // round-to-nearest-even
    return (unsigned short)(u >> 16);
}

// ---------------------------------------------------------------------------
// k_static: sectioned batch-independent prep (regbf | bt | wt | pre).
__global__ __launch_bounds__(256) void k_static(const float* __restrict__ pdirs,
                                                const float* __restrict__ sd,
                                                const float* __restrict__ jreg,
                                                const float* __restrict__ vt,
                                                const float* __restrict__ lbsw,
                                                const float* __restrict__ b25,
                                                const float* __restrict__ face,
                                                unsigned short* __restrict__ bp,
                                                unsigned short* __restrict__ rb,
                                                float* __restrict__ wbt,
                                                float* __restrict__ ws) {
    __shared__ unsigned short smem[KP * 64];     // 28 KB, reused per section
    int b = blockIdx.x;
    int tid = threadIdx.x;

    if (b < NB_REGBF) {
        int t = b * 256 + tid;
        int k = t / VP2, v = t - k * VP2;
        float val = 0.f;
        if (v < V && k < NK)
            val = (k < 25) ? b25[(size_t)k * V + v] : face[(size_t)(k - 25) * V + v];
        rb[t] = f2bf(val);
        return;
    }
    b -= NB_REGBF;
    if (b < NB_BT) {
        int c0 = b * 64;
#pragma unroll 4
        for (int i = 0; i < 56; ++i) {
            int e = tid + 256 * i;
            int k = e >> 6, cl = e & 63;
            int col = c0 + cl;
            float v = 0.f;
            if (col < V3) {
                if (k < NP) v = pdirs[(size_t)k * V3 + col];
                else if (k < NP + NB) v = sd[(size_t)(k - NP) * V3 + col];
            }
            smem[k * 64 + cl] = f2bf(v);
        }
        __syncthreads();
        for (int i = 0; i < 7; ++i) {
            int e = tid + 256 * i;
            int cl = e & 63, kc = e >> 6;
            s16x8 r;
#pragma unroll
            for (int j = 0; j < 8; ++j) r[j] = (short)smem[(kc * 8 + j) * 64 + cl];
            *reinterpret_cast<s16x8*>(&bp[(size_t)(c0 + cl) * KP + kc * 8]) = r;
        }
        return;
    }
    b -= NB_BT;
    if (b < NB_WT) {
        float* t = reinterpret_cast<float*>(smem);
        int v0 = b * 256;
        for (int e = tid; e < 256 * 24; e += 256) {
            int g = v0 * 24 + e;
            float val = (g < V * NJ) ? lbsw[g] : 0.f;
            int vv = e / 24, j = e - vv * 24;
            t[vv * 25 + j] = val;
        }
        __syncthreads();
        for (int j = 0; j < NJ; ++j)
            wbt[(size_t)j * VP2 + v0 + tid] = t[tid * 25 + j];
        return;
    }
    b -= NB_WT;
    // pre: SJ / Jt, block per jc, shuffle reduce
    int jc = b;
    int j = jc / 3, c = jc % 3;
    float acc[NB + 1];
#pragma unroll
    for (int t = 0; t <= NB; ++t) acc[t] = 0.f;
    for (int v = tid; v < V; v += 256) {
        float w = jreg[(size_t)j * V + v];
        int col = v * 3 + c;
#pragma unroll
        for (int k = 0; k < NB; ++k) acc[k] += w * sd[(size_t)k * V3 + col];
        acc[NB] += w * vt[col];
    }
    float* red = reinterpret_cast<float*>(smem);
    int lane = tid & 63, w64 = tid >> 6;
#pragma unroll
    for (int t = 0; t <= NB; ++t) {
        float a = acc[t];
#pragma unroll
        for (int s = 1; s < 64; s <<= 1) a += __shfl_xor(a, s, 64);
        if (lane == 0) red[w64 * 16 + t] = a;
    }
    __syncthreads();
    if (tid <= NB) {
        float s = red[tid] + red[16 + tid] + red[32 + tid] + red[48 + tid];
        if (tid < NB) ws[SJ_OFF + (size_t)tid * 72 + jc] = s;
        else          ws[JT_OFF + jc] = s;
    }
}

// ---------------------------------------------------------------------------
// k_head: scale + J + apf + FK, one 64-thread block (1 wave) per n.
__global__ __launch_bounds__(64) void k_head(const float* __restrict__ pose,
                                             const float* __restrict__ betas,
                                             const float* __restrict__ vt,
                                             const float* __restrict__ sd,
                                             float* __restrict__ ws,
                                             unsigned short* __restrict__ apf) {
    int n = blockIdx.x;
    int tid = threadIdx.x;
    __shared__ float sval[4];
    __shared__ float Jl[NJ * 3];
    __shared__ float G[NJ * 12];

    const int idx4[4] = {2802 * 3 + 1, 6262 * 3 + 1, 2237 * 3 + 1, 6728 * 3 + 1};
    if (tid < 4) {
        float a = vt[idx4[tid]];
#pragma unroll
        for (int k = 0; k < NB; ++k)
            a += betas[n * NB + k] * sd[(size_t)k * V3 + idx4[tid]];
        sval[tid] = a;
    }
    __syncthreads();
    float scale = 1.66f / (sval[0] + sval[1] - sval[2] - sval[3]);
    if (tid == 0) ws[SCALE_OFF + n] = scale;

    for (int k = tid; k < KP; k += 64) {
        float v = 0.f;
        if (k < NP) {
            v = pose[(size_t)n * 216 + 9 + k];
            int km = k % 9;
            if (km == 0 || km == 4 || km == 8) v -= 1.f;
        } else if (k < NP + NB) {
            v = scale * betas[n * NB + (k - NP)];
        }
        apf[(size_t)n * KP + k] = f2bf(v);
    }
    for (int e = tid; e < 72; e += 64) {
        float a = ws[JT_OFF + e];
#pragma unroll
        for (int k = 0; k < NB; ++k)
            a += betas[n * NB + k] * ws[SJ_OFF + (size_t)k * 72 + e];
        Jl[e] = scale * a;
    }
    __syncthreads();

    const int par[NJ] = {0,0,0,0,1,2,3,4,5,6,7,8,9,9,9,12,13,14,16,17,18,19,20,21};
    if (tid < 12) {
        int r = tid >> 2, c = tid & 3;
        G[tid] = (c < 3) ? pose[(size_t)n * 216 + r * 3 + c] : Jl[r];
    }
    __syncthreads();
    for (int i = 1; i < NJ; ++i) {
        int p = par[i];
        if (tid < 12) {
            int r = tid >> 2, c = tid & 3;
            const float* gp = &G[p * 12 + r * 4];
            float v;
            if (c < 3) {
                const float* Ri = pose + (size_t)n * 216 + i * 9;
                v = gp[0] * Ri[0 * 3 + c] + gp[1] * Ri[1 * 3 + c] + gp[2] * Ri[2 * 3 + c];
            } else {
                float t0 = Jl[i * 3 + 0] - Jl[p * 3 + 0];
                float t1 = Jl[i * 3 + 1] - Jl[p * 3 + 1];
                float t2 = Jl[i * 3 + 2] - Jl[p * 3 + 2];
                v = gp[0] * t0 + gp[1] * t1 + gp[2] * t2 + gp[3];
            }
            G[i * 12 + tid] = v;
        }
        __syncthreads();
    }
    for (int idx = tid; idx < 288; idx += 64) {
        int j = idx / 12, rc = idx - j * 12;
        int r = rc >> 2, c = rc & 3;
        float v;
        if (c < 3) v = G[j * 12 + rc];
        else {
            const float* g = &G[j * 12 + r * 4];
            v = g[3] - (g[0] * Jl[j * 3 + 0] + g[1] * Jl[j * 3 + 1] + g[2] * Jl[j * 3 + 2]);
        }
        ws[A_OFF + (size_t)n * 288 + idx] = v;
    }
}

// ---------------------------------------------------------------------------
// Pose MFMA GEMM: vp[n][col] = A[n][:224].B[:224][col] + scale[n]*vt[col]
__global__ __launch_bounds__(256) void k_gemm(const unsigned short* __restrict__ apf,
                                              const unsigned short* __restrict__ bp,
                                              const float* __restrict__ vt,
                                              const float* __restrict__ ws,
                                              float* __restrict__ vp) {
    int tid = threadIdx.x;
    int lane = tid & 63;
    int w = tid >> 6;
    int m = lane & 15, q = lane >> 4;
    int n0 = blockIdx.y * 64 + w * 16;
    int c0 = blockIdx.x * 64;

    const unsigned short* arow = apf + (size_t)(n0 + m) * KP + q * 8;
    const unsigned short* b0 = bp + (size_t)(c0 + m) * KP + q * 8;
    const unsigned short* b1 = b0 + 16 * KP;
    const unsigned short* b2 = b0 + 32 * KP;
    const unsigned short* b3 = b0 + 48 * KP;

    f32x4 acc0 = {0.f, 0.f, 0.f, 0.f};
    f32x4 acc1 = acc0, acc2 = acc0, acc3 = acc0;
#pragma unroll
    for (int kk = 0; kk < 7; ++kk) {
        s16x8 a = *reinterpret_cast<const s16x8*>(arow + kk * 32);
        acc0 = __builtin_amdgcn_mfma_f32_16x16x32_bf16(
            a, *reinterpret_cast<const s16x8*>(b0 + kk * 32), acc0, 0, 0, 0);
        acc1 = __builtin_amdgcn_mfma_f32_16x16x32_bf16(
            a, *reinterpret_cast<const s16x8*>(b1 + kk * 32), acc1, 0, 0, 0);
        acc2 = __builtin_amdgcn_mfma_f32_16x16x32_bf16(
            a, *reinterpret_cast<const s16x8*>(b2 + kk * 32), acc2, 0, 0, 0);
        acc3 = __builtin_amdgcn_mfma_f32_16x16x32_bf16(
            a, *reinterpret_cast<const s16x8*>(b3 + kk * 32), acc3, 0, 0, 0);
    }
    float sc[4];
#pragma unroll
    for (int r = 0; r < 4; ++r) sc[r] = ws[SCALE_OFF + n0 + q * 4 + r];

    f32x4 accs[4] = {acc0, acc1, acc2, acc3};
#pragma unroll
    for (int ct = 0; ct < 4; ++ct) {
        int col = c0 + ct * 16 + m;
        if (col < V3) {
            float vtc = vt[col];
#pragma unroll
            for (int r = 0; r < 4; ++r) {
                int n = n0 + q * 4 + r;
                vp[(size_t)n * V3 + col] = accs[ct][r] + sc[r] * vtc;
            }
        }
    }
}

// ---------------------------------------------------------------------------
// k_lbs v5: q-form, paired v (f32x2 -> v_pk_fma_f32), j-outer so each wbt
// pair is loaded once and reused across 4 n. V is even, so a pair is either
// fully valid or fully pad.
__global__ __launch_bounds__(256, 4) void k_lbs(const float* __restrict__ wbt,
                                                const float* __restrict__ trans,
                                                const float* __restrict__ ws,
                                                unsigned short* __restrict__ vb) {
    int tid = threadIdx.x;
    int idx = blockIdx.x * 256 + tid;        // pair index
    if (idx >= VP2 / 2) return;              // 3456
    int v0 = idx * 2;
    int n0 = blockIdx.y * 4;
    bool valid = (v0 < V);

    f32x2 px[4], py[4], pz[4];
#pragma unroll
    for (int nn = 0; nn < 4; ++nn) {
        f32x2 a = {0.f, 0.f}, b = a, c = a;
        if (valid) {
            const float* vp = ws + VP_OFF + (size_t)(n0 + nn) * V3 + (size_t)3 * v0;
            a = *reinterpret_cast<const f32x2*>(vp);
            b = *reinterpret_cast<const f32x2*>(vp + 2);
            c = *reinterpret_cast<const f32x2*>(vp + 4);
        }
        px[nn] = (f32x2){a.x, b.y};
        py[nn] = (f32x2){a.y, c.x};
        pz[nn] = (f32x2){b.x, c.y};
    }
    f32x2 ax[4], ay[4], az[4];
#pragma unroll
    for (int nn = 0; nn < 4; ++nn) {
        float tx = trans[(n0 + nn) * 3 + 0];
        float ty = trans[(n0 + nn) * 3 + 1];
        float tz = trans[(n0 + nn) * 3 + 2];
        ax[nn] = (f32x2){tx, tx};
        ay[nn] = (f32x2){ty, ty};
        az[nn] = (f32x2){tz, tz};
    }
    const float* A0 = ws + A_OFF + (size_t)n0 * 288;     // block-uniform
#pragma unroll
    for (int j = 0; j < NJ; ++j) {
        f32x2 w2 = *reinterpret_cast<const f32x2*>(wbt + (size_t)j * VP2 + v0);
#pragma unroll
        for (int nn = 0; nn < 4; ++nn) {
            const float* a = A0 + nn * 288 + j * 12;     // uniform -> s_load
            f32x2 qx = px[nn] * a[0] + py[nn] * a[1]  + pz[nn] * a[2]  + (f32x2){a[3], a[3]};
            f32x2 qy = px[nn] * a[4] + py[nn] * a[5]  + pz[nn] * a[6]  + (f32x2){a[7], a[7]};
            f32x2 qz = px[nn] * a[8] + py[nn] * a[9]  + pz[nn] * a[10] + (f32x2){a[11], a[11]};
            ax[nn] += w2 * qx;
            ay[nn] += w2 * qy;
            az[nn] += w2 * qz;
        }
    }
#pragma unroll
    for (int nn = 0; nn < 4; ++nn) {
        f32x2 x = ax[nn], y = ay[nn], z = az[nn];
        if (!valid) {
            x = (f32x2){0.f, 0.f}; y = x; z = x;
        }
        size_t base = (size_t)(n0 + nn) * 3 * VP2 + v0;
        ushort2 sx = {f2bf(x.x), f2bf(x.y)};
        ushort2 sy = {f2bf(y.x), f2bf(y.y)};
        ushort2 sz = {f2bf(z.x), f2bf(z.y)};
        *reinterpret_cast<ushort2*>(vb + base)           = sx;
        *reinterpret_cast<ushort2*>(vb + base + VP2)     = sy;
        *reinterpret_cast<ushort2*>(vb + base + 2 * VP2) = sz;
    }
}

// ---------------------------------------------------------------------------
// k_regm v2: block = one nc-tile x ALL 6 k-tiles (vb read once; rb L2-resident),
// v-split 2 across grid.y, 4-wave K-split inside, atomicAdd to out.
__global__ __launch_bounds__(256) void k_regm(const unsigned short* __restrict__ rb,
                                              const unsigned short* __restrict__ vb,
                                              float* __restrict__ out) {
    int tid = threadIdx.x;
    int lane = tid & 63, w = tid >> 6;
    int m = lane & 15, q = lane >> 4;
    int nct = blockIdx.x;                    // 0..95
    int half = blockIdx.y;                   // 0..1

    const unsigned short* brow = vb + (size_t)(nct * 16 + m) * VP2 + q * 8;
    const unsigned short* abase = rb + (size_t)m * VP2 + q * 8;
    int vstart = half * 3456 + w * 864;      // 27 steps of 32 per wave

    f32x4 acc[6];
#pragma unroll
    for (int kt = 0; kt < 6; ++kt) acc[kt] = (f32x4){0.f, 0.f, 0.f, 0.f};

    for (int s = 0; s < 27; ++s) {
        int off = vstart + s * 32;
        s16x8 b = *reinterpret_cast<const s16x8*>(brow + off);
#pragma unroll
        for (int kt = 0; kt < 6; ++kt) {
            s16x8 a = *reinterpret_cast<const s16x8*>(abase + (size_t)kt * 16 * VP2 + off);
            acc[kt] = __builtin_amdgcn_mfma_f32_16x16x32_bf16(a, b, acc[kt], 0, 0, 0);
        }
    }
    __shared__ float sm[4][6][256];          // 24 KB
#pragma unroll
    for (int kt = 0; kt < 6; ++kt)
#pragma unroll
        for (int r = 0; r < 4; ++r)
            sm[w][kt][(q * 4 + r) * 16 + m] = acc[kt][r];
    __syncthreads();
    for (int e = tid; e < 6 * 256; e += 256) {
        int kt = e >> 8, i = e & 255;
        float s = sm[0][kt][i] + sm[1][kt][i] + sm[2][kt][i] + sm[3][kt][i];
        int k = kt * 16 + (i >> 4);
        int nc = nct * 16 + (i & 15);
        if (k < NK) {
            int n = nc / 3, c = nc - n * 3;
            atomicAdd(&out[(size_t)n * (NK * 3) + k * 3 + c], s);
        }
    }
}

// ---------------------------------------------------------------------------
extern "C" void kernel_launch(void* const* d_in, const int* in_sizes, int n_in,
                              void* d_out, int out_size, void* d_ws, size_t ws_size,
                              hipStream_t stream) {
    const float* pose  = (const float*)d_in[0];
    const float* betas = (const float*)d_in[1];
    const float* trans = (const float*)d_in[2];
    const float* vt    = (const float*)d_in[3];
    const float* sd    = (const float*)d_in[4];
    const float* jreg  = (const float*)d_in[5];
    const float* pdirs = (const float*)d_in[6];
    const float* lbsw  = (const float*)d_in[7];
    const float* b25   = (const float*)d_in[8];
    const float* face  = (const float*)d_in[9];
    float* ws  = (float*)d_ws;
    float* out = (float*)d_out;
    unsigned short* bf  = (unsigned short*)(ws + BF_OFF);
    unsigned short* apf = bf + APF_U;
    unsigned short* bp  = bf + BP_U;
    unsigned short* rb  = bf + RB_U;
    unsigned short* vb  = bf + VB_U;
    float* wbt = ws + WT_OFF;

    hipMemsetAsync(d_out, 0, (size_t)out_size * sizeof(float), stream);

    k_static<<<NB_STATIC, 256, 0, stream>>>(pdirs, sd, jreg, vt, lbsw, b25, face,
                                            bp, rb, wbt, ws);
    k_head  <<<N, 64, 0, stream>>>(pose, betas, vt, sd, ws, apf);
    k_gemm  <<<dim3(BP_COLS / 64, N / 64), 256, 0, stream>>>(apf, bp, vt, ws, ws + VP_OFF);
    k_lbs   <<<dim3((VP2 / 2 + 255) / 256, N / 4), 256, 0, stream>>>(wbt, trans, ws, vb);
    k_regm  <<<dim3(96, 2), 256, 0, stream>>>(rb, vb, out);
}